// Round 12
// baseline (414.239 us; speedup 1.0000x reference)
//
#include <hip/hip_runtime.h>

#define NT 32
#define EPSF 1e-8f

// ================= Gram kernel =================
// r13: ONLY change = epilogue. The old epilogue did ~1M fp64 global
// atomicAdd over 1024 addresses (128 cache lines -> ~8k line-serialized RMWs
// per line, est. 15-25us dead tail, no VALU -> consistent with r11's
// VALUBusy 49% and L3-warm reps not being faster). New: coalesced per-block
// partial stores (4MB) + reduce_kernel (fp64 fixed-order sum; the old atomic
// order was nondeterministic and absmax was 0.0, so order-independence at
// output precision is already proven).
// Main loop BYTE-IDENTICAL to r7..r12 (verified; bank-conflict 0).
// Attribution (r8/r11/r12 arithmetic): gram ~83us is the ONLY optimizable
// term; solver ~2-5us (converges early); fills ~320us harness-fixed.
#define TILE_COLS 64
#define GR_THREADS 256
#define WAVES_PB 4
#define TILES_PW 8    // cols/wave = 512, cols/block = 2048 -> grid = 1024

__global__ __launch_bounds__(GR_THREADS, 1)
void gram_kernel(const float* __restrict__ vecs, float* __restrict__ part, int D)
{
    __shared__ __align__(16) float tile[WAVES_PB][TILE_COLS * 32];
    __shared__ float Gpart[NT * NT];

    const int tid  = threadIdx.x;
    const int wave = tid >> 6;
    const int lane = tid & 63;

    for (int e = tid; e < NT * NT; e += GR_THREADS) Gpart[e] = 0.0f;
    __syncthreads();

    float* my = tile[wave];
    const int swz = lane & 7;

    const int cj = lane >> 4;
    const int pi = (lane >> 2) & 3;
    const int pk = lane & 3;

    float acc[8][8];
#pragma unroll
    for (int r = 0; r < 8; r++)
#pragma unroll
        for (int c = 0; c < 8; c++) acc[r][c] = 0.0f;

    const unsigned base0 = (unsigned)blockIdx.x * (WAVES_PB * TILES_PW * TILE_COLS)
                         + (unsigned)wave * (TILES_PW * TILE_COLS) + (unsigned)lane;

    float pre[32];
#pragma unroll
    for (int r = 0; r < 32; r++)
        pre[r] = (vecs + (size_t)r * (size_t)D)[base0];

    for (int t = 0; t < TILES_PW; t++) {
#pragma unroll
        for (int g = 0; g < 8; g++) {
            float4 w = make_float4(pre[4 * g + 0], pre[4 * g + 1],
                                   pre[4 * g + 2], pre[4 * g + 3]);
            *(float4*)(my + lane * 32 + ((g ^ swz) << 2)) = w;
        }
        if (t + 1 < TILES_PW) {
            const unsigned off = base0 + (unsigned)(t + 1) * TILE_COLS;
#pragma unroll
            for (int r = 0; r < 32; r++)
                pre[r] = (vecs + (size_t)r * (size_t)D)[off];
        }
        asm volatile("" ::: "memory");
#pragma unroll
        for (int jt = 0; jt < 16; jt++) {
            const int j = (jt << 2) + cj;
            const float* col = my + j * 32;
            const int js = j & 7;
            const float4 a0 = *(const float4*)(col + (((2 * pi) ^ js) << 2));
            const float4 a1 = *(const float4*)(col + (((2 * pi + 1) ^ js) << 2));
            const float4 b0 = *(const float4*)(col + (((2 * pk) ^ js) << 2));
            const float4 b1 = *(const float4*)(col + (((2 * pk + 1) ^ js) << 2));
            const float a[8] = {a0.x, a0.y, a0.z, a0.w, a1.x, a1.y, a1.z, a1.w};
            const float b[8] = {b0.x, b0.y, b0.z, b0.w, b1.x, b1.y, b1.z, b1.w};
#pragma unroll
            for (int r = 0; r < 8; r++)
#pragma unroll
                for (int c = 0; c < 8; c++)
                    acc[r][c] = fmaf(a[r], b[c], acc[r][c]);
        }
    }

    // fold cj column-split into per-block fp32 partials (unchanged)
#pragma unroll
    for (int r = 0; r < 8; r++)
#pragma unroll
        for (int c = 0; c < 8; c++) {
            float v = acc[r][c];
            v += __shfl_xor(v, 16);
            v += __shfl_xor(v, 32);
            if (lane < 16)
                atomicAdd(&Gpart[(8 * pi + r) * NT + (8 * pk + c)], v);
        }
    __syncthreads();
    // r13 epilogue: coalesced plain stores of the block partial (no atomics)
    float* myPart = part + (size_t)blockIdx.x * (NT * NT);
    for (int e = tid; e < NT * NT; e += GR_THREADS)
        myPart[e] = Gpart[e];
}

// ===== reduce_kernel: Gd[e] = sum_b part[b][e] in fp64, fixed order. =====
// 256 blocks x 1 wave; block g owns entry quad [4g, 4g+4). Thread t sums
// b = t + 64j (j=0..15) via float4 loads, then 6-round shfl butterfly.
// 1M floats total; ~262k float4 loads spread over 256 CUs; latency-trivial.
__global__ __launch_bounds__(64)
void reduce_kernel(const float* __restrict__ part, double* __restrict__ Gd)
{
    const int g = blockIdx.x;
    const int t = threadIdx.x;
    double s0 = 0.0, s1 = 0.0, s2 = 0.0, s3 = 0.0;
#pragma unroll
    for (int j = 0; j < 16; j++) {
        const float4 v = *(const float4*)(part
            + (size_t)(t + 64 * j) * (NT * NT) + 4 * g);
        s0 += (double)v.x; s1 += (double)v.y;
        s2 += (double)v.z; s3 += (double)v.w;
    }
#pragma unroll
    for (int m = 1; m < 64; m <<= 1) {
        s0 += __shfl_xor(s0, m);
        s1 += __shfl_xor(s1, m);
        s2 += __shfl_xor(s2, m);
        s3 += __shfl_xor(s3, m);
    }
    if (t == 0) {
        Gd[4 * g + 0] = s0;
        Gd[4 * g + 1] = s1;
        Gd[4 * g + 2] = s2;
        Gd[4 * g + 3] = s3;
    }
}

// ================= Solver kernel (BYTE-IDENTICAL r12, verified) ==========
// ~2-5us total (converges early; r11 arithmetic). Not worth touching.
template<int CTRL>
__device__ __forceinline__ float dpp0(float x) {
    return __int_as_float(__builtin_amdgcn_update_dpp(
        0, __float_as_int(x), CTRL, 0xF, 0xF, true));
}
template<int CTRL>
__device__ __forceinline__ float dppk(float oldv, float x) {
    return __int_as_float(__builtin_amdgcn_update_dpp(
        __float_as_int(oldv), __float_as_int(x), CTRL, 0xF, 0xF, false));
}
__device__ __forceinline__ float rdlane(float x, int l) {
    return __int_as_float(__builtin_amdgcn_readlane(__float_as_int(x), l));
}

__device__ __forceinline__ float bsum32u(float v) {
    v += dpp0<0x111>(v);
    v += dpp0<0x112>(v);
    v += dpp0<0x114>(v);
    v += dpp0<0x118>(v);
    return rdlane(v, 15) + rdlane(v, 31);
}
__device__ __forceinline__ float bmin32u(float v) {
    v = fminf(v, dppk<0x111>(v, v));
    v = fminf(v, dppk<0x112>(v, v));
    v = fminf(v, dppk<0x114>(v, v));
    v = fminf(v, dppk<0x118>(v, v));
    return fminf(rdlane(v, 15), rdlane(v, 31));
}

__global__ __launch_bounds__(64)
void solver_kernel(const double* __restrict__ Gd, float* __restrict__ out)
{
    __shared__ float Gsh[NT * 33];
    __shared__ __align__(16) float xb0[64];
    __shared__ __align__(16) float xb1[64];
    __shared__ __align__(16) float xb2[64];

    const int lane = threadIdx.x;
    const int e = lane & 31;
    const int h = lane >> 5;

    for (int t2 = 0; t2 < 16; t2++) {
        int idx = t2 * 64 + lane;
        Gsh[(idx >> 5) * 33 + (idx & 31)] = (float)Gd[idx];
    }
    __syncthreads();

    float Grow[16];
#pragma unroll
    for (int k = 0; k < 16; k++)
        Grow[k] = Gsh[e * 33 + 16 * h + k];

    const int hb = h * 48;
    const float4* xr0 = (const float4*)(xb0 + hb);
    const float4* xr1 = (const float4*)(xb1 + hb);
    const float4* xr2 = (const float4*)(xb2 + hb);

    auto mv = [&](const float4* xr) -> float {
        const float4 q0 = xr[0], q1 = xr[1], q2 = xr[2], q3 = xr[3];
        const float xv[16] = {q0.x, q0.y, q0.z, q0.w, q1.x, q1.y, q1.z, q1.w,
                              q2.x, q2.y, q2.z, q2.w, q3.x, q3.y, q3.z, q3.w};
        float a0 = 0.0f, a1 = 0.0f;
#pragma unroll
        for (int s = 0; s < 16; s += 2) {
            a0 = fmaf(Grow[s + 0], xv[s + 0], a0);
            a1 = fmaf(Grow[s + 1], xv[s + 1], a1);
        }
        float half = a0 + a1;
        return half + __shfl_xor(half, 32);
    };

    float bestCost = INFINITY, bestGamma = 0.0f;
    int bestEnc = 0x7FFFFFFF;
    for (int a = 0; a < NT - 1; a++) {
        int b = a + 1 + lane;
        if (b < NT) {
            float v11 = Gsh[a * 33 + a];
            float v12 = Gsh[a * 33 + b];
            float v22 = Gsh[b * 33 + b];
            float g = (v22 - v12) / (v11 + v22 - 2.0f * v12 + EPSF);
            float c = v22 + g * (v12 - v22);
            float gamma = (v12 >= v22) ? 0.0f : g;
            float cost  = (v12 >= v22) ? v22 : c;
            if (v12 >= v11) { gamma = 1.0f; cost = v11; }
            int enc = a * NT + b;
            if (cost < bestCost) { bestCost = cost; bestEnc = enc; bestGamma = gamma; }
        }
    }
#pragma unroll
    for (int m = 1; m < 64; m <<= 1) {
        float oc = __shfl_xor(bestCost, m);
        int   oe = __shfl_xor(bestEnc, m);
        float og = __shfl_xor(bestGamma, m);
        if (oc < bestCost || (oc == bestCost && oe < bestEnc)) {
            bestCost = oc; bestEnc = oe; bestGamma = og;
        }
    }
    const int bi = bestEnc >> 5, bj = bestEnc & 31;

    float sol = 0.0f;
    if (e == bi) sol = bestGamma;
    if (e == bj) sol = 1.0f - bestGamma;

    xb0[lane] = sol;

    float GsolRec = 0.0f;    // valid when (it & 3) != 0

    for (int it = 0; it < 250; it++) {
        float Gsol = ((it & 3) == 0) ? mv(xr0) : GsolRec;

        float grad = -Gsol;
        float proj = grad - bsum32u(grad) * 0.03125f;

        float tm1 = (proj < 0.0f) ? (-sol / proj) : INFINITY;
        float tm2 = (proj > 0.0f) ? ((1.0f - sol) / proj) : INFINITY;
        float m1 = bmin32u((tm1 > 1e-7f) ? tm1 : INFINITY);
        float m2 = bmin32u((tm2 > 1e-7f) ? tm2 : INFINITY);
        float t = __builtin_isinf(m1) ? 1.0f : m1;
        t = fminf(t, m2);
        float nxt = fmaf(proj, t, sol);

        int nb = __float_as_int(nxt);
        unsigned u = (unsigned)nb ^ ((nb < 0) ? 0xFFFFFFFFu : 0x80000000u);

        xb1[lane] = nxt;
        const float4 r0 = xr1[0], r1 = xr1[1], r2 = xr1[2], r3 = xr1[3];
        const float xj16[16] = {r0.x, r0.y, r0.z, r0.w, r1.x, r1.y, r1.z, r1.w,
                                r2.x, r2.y, r2.z, r2.w, r3.x, r3.y, r3.z, r3.w};

        int rank = 0;
        float S = 0.0f;
        const int dtie = e - 16 * h;
#pragma unroll
        for (int s = 0; s < 16; s++) {
            float xj = xj16[s];
            int nbj = __float_as_int(xj);
            unsigned uj = (unsigned)nbj ^ ((nbj < 0) ? 0xFFFFFFFFu : 0x80000000u);
            bool gt = (uj > u) || ((uj == u) && (s < dtie));
            rank += gt ? 1 : 0;
            S += gt ? xj : 0.0f;
        }
        rank += __shfl_xor(rank, 32);
        S += __shfl_xor(S, 32);

        float total = bsum32u(nxt);

        float cand = (S - 1.0f) / (float)rank;
        bool cond = (rank >= 1) && (cand > nxt);
        float rmin = bmin32u(cond ? (float)rank : INFINITY);
        unsigned long long msk = __ballot(cond && ((float)rank == rmin));
        int src = (int)__ffsll(msk) - 1;
        float tmax = (msk == 0ull)
                   ? (total - 1.0f) * 0.03125f
                   : rdlane(cand, src);
        float newp = fmaxf(nxt - tmax, 0.0f);

        xb2[lane] = newp;
        float Gn = mv(xr2);

        float z = (h == 0) ? (sol * Gsol) : (newp * Gn);
        z += dpp0<0x111>(z);
        z += dpp0<0x112>(z);
        z += dpp0<0x114>(z);
        z += dpp0<0x118>(z);
        float v11 = rdlane(z, 15) + rdlane(z, 31);
        float v22 = rdlane(z, 47) + rdlane(z, 63);
        float v12 = bsum32u(sol * Gn);

        float g = (v22 - v12) / (v11 + v22 - 2.0f * v12 + EPSF);
        float gamma = (v12 >= v22) ? 0.0f : g;
        gamma = (v12 >= v11) ? 1.0f : gamma;

        float new_sol = gamma * sol + (1.0f - gamma) * newp;

        GsolRec = fmaf(gamma, Gsol, (1.0f - gamma) * Gn);

        float diff = bsum32u(fabsf(new_sol - sol));
        if (diff < 1e-6f) break;
        sol = new_sol;
        xb0[lane] = sol;
    }
    if (lane < NT) out[lane] = sol;
}

extern "C" void kernel_launch(void* const* d_in, const int* in_sizes, int n_in,
                              void* d_out, int out_size, void* d_ws, size_t ws_size,
                              hipStream_t stream) {
    const float* vecs = (const float*)d_in[0];
    float* out = (float*)d_out;
    double* Gd = (double*)d_ws;                         // 8 KB at offset 0
    float* part = (float*)((char*)d_ws + (1 << 20));    // 4 MB partials
    const int D = in_sizes[0] / NT;      // 2097152

    // no memset: reduce_kernel fully overwrites Gd

    const int cols_per_block = WAVES_PB * TILES_PW * TILE_COLS;  // 2048
    const int grid = D / cols_per_block;                          // 1024
    gram_kernel<<<grid, GR_THREADS, 0, stream>>>(vecs, part, D);
    reduce_kernel<<<NT * NT / 4, 64, 0, stream>>>(part, Gd);
    solver_kernel<<<1, 64, 0, stream>>>(Gd, out);
}